// Round 4
// baseline (267.465 us; speedup 1.0000x reference)
//
#include <hip/hip_runtime.h>
#include <hip/hip_bf16.h>

// LoKr: out = x @ kron(w1, a@b).T * S, factored into 3 small GEMMs.
// x view: [65536 A-rows (pos*8+ij) x 512 il], b: [64 r x 512 il],
// a: [512 ok x 64 r], out row (pos*8+oi) x 512 ok.
//
// R5->R7: single-variable experiment — NON-TEMPORAL out stores.
// R3/R4/R5 (three structurally different kernels: LDS-staged/barriered,
// direct-load/barrier-free, 2-8 blocks/CU) ALL pinned at 93-98us with all
// pipes idle -> the bottleneck is none of the things we varied. The one
// untouched common path: out writes allocate in the 256MB LLC, and
// x(134MB)+out(134MB) > 256MB forces permanent LLC thrash (stable ~66MB
// x re-fetch = half of x evicted every pass). nt stores stream out past
// the LLC: x becomes LLC-resident, out stops paying allocate/evict.
// Kernel structure is otherwise byte-identical to R5.

typedef __attribute__((ext_vector_type(4))) float f32x4;
typedef __attribute__((ext_vector_type(8))) short s16x8;

__device__ inline unsigned short f2bf(float f) {
    unsigned u = __float_as_uint(f);
    u += 0x7FFF + ((u >> 16) & 1);   // round-to-nearest-even
    return (unsigned short)(u >> 16);
}

__device__ inline s16x8 pack8(float4 lo, float4 hi) {
    s16x8 h;
    h[0] = (short)f2bf(lo.x); h[1] = (short)f2bf(lo.y);
    h[2] = (short)f2bf(lo.z); h[3] = (short)f2bf(lo.w);
    h[4] = (short)f2bf(hi.x); h[5] = (short)f2bf(hi.y);
    h[6] = (short)f2bf(hi.z); h[7] = (short)f2bf(hi.w);
    return h;
}

// Precompute: b -> bf16 [64][512] (row=r, col=il), a -> bf16 [512][64]
// (row=ok, col=r), w1s = w1 * (1/64). Into d_ws (re-poisoned each call).
__global__ void lokr_pre(const float* __restrict__ w1,
                         const float* __restrict__ a,
                         const float* __restrict__ b,
                         unsigned short* __restrict__ b_bf,
                         unsigned short* __restrict__ a_bf,
                         float* __restrict__ w1s) {
    int i = blockIdx.x * 256 + threadIdx.x;
    if (i < 32768) {
        b_bf[i] = f2bf(b[i]);
        a_bf[i] = f2bf(a[i]);
    }
    if (i < 64) w1s[i] = w1[i] * (1.0f / 64.0f);
}

#define LSTR 72   // LDS row stride in shorts (64 + 8 pad)

__global__ __launch_bounds__(128, 4) void lokr_main(
    const float* __restrict__ x,
    const unsigned short* __restrict__ b_bf,
    const unsigned short* __restrict__ a_bf,
    const float* __restrict__ w1s,
    float* __restrict__ out)
{
    __shared__ __attribute__((aligned(16))) unsigned short vs[32 * LSTR];
    __shared__ float w1_s[64];

    const int t    = threadIdx.x;
    const int wave = t >> 6;
    const int lane = t & 63;
    const int col  = lane & 15;   // MFMA: A row / B col / C col
    const int quad = lane >> 4;
    const long rowbase = (long)blockIdx.x * 32;
    const long wrow    = rowbase + wave * 16;   // this wave's 16 A-rows

    // both waves write identical values -> benign race, no barrier needed
    w1_s[lane] = w1s[lane];

    // Lane's A-fragment source: row wrow+col, k-chunk quad*8 (+32 for a1).
    const float* xw = x + (wrow + col) * 512 + quad * 8;
    // b-frag source: r = rt*16+col, k = s*64 + quad*8 (+32).
    const unsigned short* bw = b_bf + col * 512 + quad * 8;

    // ---- stage 1: T[16 rows x 64 r], no LDS, no barriers ----
    f32x4 acc[4];
    #pragma unroll
    for (int rt = 0; rt < 4; ++rt) acc[rt] = (f32x4){0.f, 0.f, 0.f, 0.f};

    float4 xb[4];
    xb[0] = *(const float4*)(xw);
    xb[1] = *(const float4*)(xw + 4);
    xb[2] = *(const float4*)(xw + 32);
    xb[3] = *(const float4*)(xw + 36);

    s16x8 bc[4][2];
    #pragma unroll
    for (int rt = 0; rt < 4; ++rt) {
        bc[rt][0] = *(const s16x8*)(bw + rt * 8192);
        bc[rt][1] = *(const s16x8*)(bw + rt * 8192 + 32);
    }

    #pragma unroll 2
    for (int s = 0; s < 8; ++s) {
        // consume current x first (frees xb regs for the prefetch)
        s16x8 a0 = pack8(xb[0], xb[1]);
        s16x8 a1 = pack8(xb[2], xb[3]);
        // prefetch slab s+1 (b from L2 first, then x from HBM/L3)
        s16x8 bn[4][2];
        if (s < 7) {
            #pragma unroll
            for (int rt = 0; rt < 4; ++rt) {
                bn[rt][0] = *(const s16x8*)(bw + rt * 8192 + (s + 1) * 64);
                bn[rt][1] = *(const s16x8*)(bw + rt * 8192 + (s + 1) * 64 + 32);
            }
            const float* xg = xw + (s + 1) * 64;
            xb[0] = *(const float4*)(xg);
            xb[1] = *(const float4*)(xg + 4);
            xb[2] = *(const float4*)(xg + 32);
            xb[3] = *(const float4*)(xg + 36);
        }
        #pragma unroll
        for (int rt = 0; rt < 4; ++rt) {
            acc[rt] = __builtin_amdgcn_mfma_f32_16x16x32_bf16(a0, bc[rt][0], acc[rt], 0, 0, 0);
            acc[rt] = __builtin_amdgcn_mfma_f32_16x16x32_bf16(a1, bc[rt][1], acc[rt], 0, 0, 0);
        }
        if (s < 7) {
            #pragma unroll
            for (int rt = 0; rt < 4; ++rt) {
                bc[rt][0] = bn[rt][0]; bc[rt][1] = bn[rt][1];
            }
        }
    }

    // ---- stage 2: mix ij->oi with w1, write v (bf16) to LDS ----
    // acc[rt]: T row_local = quad*4+reg (16 rows = 2 positions x 8 ij),
    // r = rt*16+col. p = quad>>1, j = (quad&1)*4+reg; shfl_xor(16)
    // exchanges the complementary ij half; quad&1 splits the 8 oi.
    const int p   = quad >> 1;
    const int oib = (quad & 1) * 4;
    #pragma unroll
    for (int rt = 0; rt < 4; ++rt) {
        float own[4], oth[4], tij[8];
        #pragma unroll
        for (int j = 0; j < 4; ++j) own[j] = acc[rt][j];
        #pragma unroll
        for (int j = 0; j < 4; ++j) oth[j] = __shfl_xor(own[j], 16);
        if ((quad & 1) == 0) {
            #pragma unroll
            for (int j = 0; j < 4; ++j) { tij[j] = own[j]; tij[4 + j] = oth[j]; }
        } else {
            #pragma unroll
            for (int j = 0; j < 4; ++j) { tij[j] = oth[j]; tij[4 + j] = own[j]; }
        }
        #pragma unroll
        for (int oo = 0; oo < 4; ++oo) {
            float v = 0.f;
            #pragma unroll
            for (int j = 0; j < 8; ++j) v += w1_s[(oib + oo) * 8 + j] * tij[j];
            vs[(wave * 16 + p * 8 + oib + oo) * LSTR + rt * 16 + col] = f2bf(v);
        }
    }
    __syncthreads();   // the ONLY barrier: share V across the 2 waves

    // ---- stage 3: out[32 x 512] = v[32 x 64] @ a^T; wave owns 256-wide
    // ok strip. Swapped operands: C[ok][xrow] -> lane holds 4 consecutive
    // ok (quad*4+reg) for row m*16+col -> float4 NON-TEMPORAL stores.
    s16x8 va[2][2];
    #pragma unroll
    for (int m = 0; m < 2; ++m) {
        const unsigned short* vp = &vs[(m * 16 + col) * LSTR + quad * 8];
        va[m][0] = *(const s16x8*)(vp);
        va[m][1] = *(const s16x8*)(vp + 32);
    }

    const unsigned short* ab = a_bf + (wave * 256 + col) * 64 + quad * 8;
    s16x8 ac0 = *(const s16x8*)(ab);
    s16x8 ac1 = *(const s16x8*)(ab + 32);

    float* ob = out + (rowbase + col) * 512 + wave * 256 + quad * 4;

    for (int nt = 0; nt < 16; ++nt) {
        s16x8 an0, an1;
        if (nt < 15) {
            an0 = *(const s16x8*)(ab + (nt + 1) * 1024);
            an1 = *(const s16x8*)(ab + (nt + 1) * 1024 + 32);
        }
        #pragma unroll
        for (int m = 0; m < 2; ++m) {
            f32x4 c = {0.f, 0.f, 0.f, 0.f};
            c = __builtin_amdgcn_mfma_f32_16x16x32_bf16(ac0, va[m][0], c, 0, 0, 0);
            c = __builtin_amdgcn_mfma_f32_16x16x32_bf16(ac1, va[m][1], c, 0, 0, 0);
            __builtin_nontemporal_store(c, (f32x4*)(ob + (long)m * 16 * 512 + nt * 16));
        }
        if (nt < 15) { ac0 = an0; ac1 = an1; }
    }
}

extern "C" void kernel_launch(void* const* d_in, const int* in_sizes, int n_in,
                              void* d_out, int out_size, void* d_ws, size_t ws_size,
                              hipStream_t stream) {
    const float* x  = (const float*)d_in[0];  // [4,2048,4096]
    const float* w1 = (const float*)d_in[1];  // [8,8]
    const float* a  = (const float*)d_in[2];  // [512,64]
    const float* b  = (const float*)d_in[3];  // [64,512]

    unsigned short* b_bf = (unsigned short*)d_ws;          // 64 KB
    unsigned short* a_bf = b_bf + 32768;                   // 64 KB
    float*          w1s  = (float*)(a_bf + 32768);         // 256 B

    lokr_pre<<<128, 256, 0, stream>>>(w1, a, b, b_bf, a_bf, w1s);
    lokr_main<<<2048, 128, 0, stream>>>(x, b_bf, a_bf, w1s, (float*)d_out);
}

// Round 5
// 253.465 us; speedup vs baseline: 1.0552x; 1.0552x over previous
//
#include <hip/hip_runtime.h>
#include <hip/hip_bf16.h>

// LoKr: out = x @ kron(w1, a@b).T * S, factored into 3 small GEMMs.
// x view: [65536 A-rows (pos*8+ij) x 512 il], b: [64 r x 512 il],
// a: [512 ok x 64 r], out row (pos*8+oi) x 512 ok.
//
// R7->R8: NT stores done right. R7's plain NT regressed AND grew
// WRITE_SIZE 132->171MB: our scattered 16x64B-chunk store pattern can't
// write-combine without LLC allocation -> partial-line HBM writes. Now
// stage-3 C bounces through an LDS tile (aliased over the dead vs buffer)
// and streams out as linear 512B-contiguous full-line NT stores
// (128 thr x 16B = 2KB/instr). Tests the real hypothesis: the out write
// stream's LLC allocate/evict churn (which also evicts x) is the binding
// resource all four ~95us kernels shared. Stages 1-2 byte-identical R5.

typedef __attribute__((ext_vector_type(4))) float f32x4;
typedef __attribute__((ext_vector_type(8))) short s16x8;

__device__ inline unsigned short f2bf(float f) {
    unsigned u = __float_as_uint(f);
    u += 0x7FFF + ((u >> 16) & 1);   // round-to-nearest-even
    return (unsigned short)(u >> 16);
}

__device__ inline s16x8 pack8(float4 lo, float4 hi) {
    s16x8 h;
    h[0] = (short)f2bf(lo.x); h[1] = (short)f2bf(lo.y);
    h[2] = (short)f2bf(lo.z); h[3] = (short)f2bf(lo.w);
    h[4] = (short)f2bf(hi.x); h[5] = (short)f2bf(hi.y);
    h[6] = (short)f2bf(hi.z); h[7] = (short)f2bf(hi.w);
    return h;
}

// Precompute: b -> bf16 [64][512] (row=r, col=il), a -> bf16 [512][64]
// (row=ok, col=r), w1s = w1 * (1/64). Into d_ws (re-poisoned each call).
__global__ void lokr_pre(const float* __restrict__ w1,
                         const float* __restrict__ a,
                         const float* __restrict__ b,
                         unsigned short* __restrict__ b_bf,
                         unsigned short* __restrict__ a_bf,
                         float* __restrict__ w1s) {
    int i = blockIdx.x * 256 + threadIdx.x;
    if (i < 32768) {
        b_bf[i] = f2bf(b[i]);
        a_bf[i] = f2bf(a[i]);
    }
    if (i < 64) w1s[i] = w1[i] * (1.0f / 64.0f);
}

#define LSTR 72    // vs row stride in shorts (64 + 8 pad)
#define CSTR 132   // ct row stride in floats (128 + 4 pad, keeps 16B align)

__global__ __launch_bounds__(128, 4) void lokr_main(
    const float* __restrict__ x,
    const unsigned short* __restrict__ b_bf,
    const unsigned short* __restrict__ a_bf,
    const float* __restrict__ w1s,
    float* __restrict__ out)
{
    // Aliased scratch: vs (stage-2 v, 32x72 shorts = 4.6KB) then ct
    // (stage-3 C bounce, 32x132 f32 = 16.9KB). va reads drain before the
    // first ct write (barrier between).
    __shared__ __attribute__((aligned(16))) unsigned char smem[32 * CSTR * 4];
    __shared__ float w1_s[64];
    unsigned short* vs = (unsigned short*)smem;
    float*          ct = (float*)smem;

    const int t    = threadIdx.x;
    const int wave = t >> 6;
    const int lane = t & 63;
    const int col  = lane & 15;   // MFMA: A row / B col / C col
    const int quad = lane >> 4;
    const long rowbase = (long)blockIdx.x * 32;
    const long wrow    = rowbase + wave * 16;   // this wave's 16 A-rows

    // both waves write identical values -> benign race, no barrier needed
    w1_s[lane] = w1s[lane];

    // Lane's A-fragment source: row wrow+col, k-chunk quad*8 (+32 for a1).
    const float* xw = x + (wrow + col) * 512 + quad * 8;
    // b-frag source: r = rt*16+col, k = s*64 + quad*8 (+32).
    const unsigned short* bw = b_bf + col * 512 + quad * 8;

    // ---- stage 1: T[16 rows x 64 r], no LDS, no barriers ----
    f32x4 acc[4];
    #pragma unroll
    for (int rt = 0; rt < 4; ++rt) acc[rt] = (f32x4){0.f, 0.f, 0.f, 0.f};

    float4 xb[4];
    xb[0] = *(const float4*)(xw);
    xb[1] = *(const float4*)(xw + 4);
    xb[2] = *(const float4*)(xw + 32);
    xb[3] = *(const float4*)(xw + 36);

    s16x8 bc[4][2];
    #pragma unroll
    for (int rt = 0; rt < 4; ++rt) {
        bc[rt][0] = *(const s16x8*)(bw + rt * 8192);
        bc[rt][1] = *(const s16x8*)(bw + rt * 8192 + 32);
    }

    #pragma unroll 2
    for (int s = 0; s < 8; ++s) {
        // consume current x first (frees xb regs for the prefetch)
        s16x8 a0 = pack8(xb[0], xb[1]);
        s16x8 a1 = pack8(xb[2], xb[3]);
        // prefetch slab s+1 (b from L2 first, then x from HBM/L3)
        s16x8 bn[4][2];
        if (s < 7) {
            #pragma unroll
            for (int rt = 0; rt < 4; ++rt) {
                bn[rt][0] = *(const s16x8*)(bw + rt * 8192 + (s + 1) * 64);
                bn[rt][1] = *(const s16x8*)(bw + rt * 8192 + (s + 1) * 64 + 32);
            }
            const float* xg = xw + (s + 1) * 64;
            xb[0] = *(const float4*)(xg);
            xb[1] = *(const float4*)(xg + 4);
            xb[2] = *(const float4*)(xg + 32);
            xb[3] = *(const float4*)(xg + 36);
        }
        #pragma unroll
        for (int rt = 0; rt < 4; ++rt) {
            acc[rt] = __builtin_amdgcn_mfma_f32_16x16x32_bf16(a0, bc[rt][0], acc[rt], 0, 0, 0);
            acc[rt] = __builtin_amdgcn_mfma_f32_16x16x32_bf16(a1, bc[rt][1], acc[rt], 0, 0, 0);
        }
        if (s < 7) {
            #pragma unroll
            for (int rt = 0; rt < 4; ++rt) {
                bc[rt][0] = bn[rt][0]; bc[rt][1] = bn[rt][1];
            }
        }
    }

    // ---- stage 2: mix ij->oi with w1, write v (bf16) to LDS ----
    // acc[rt]: T row_local = quad*4+reg (16 rows = 2 positions x 8 ij),
    // r = rt*16+col. p = quad>>1, j = (quad&1)*4+reg; shfl_xor(16)
    // exchanges the complementary ij half; quad&1 splits the 8 oi.
    const int p   = quad >> 1;
    const int oib = (quad & 1) * 4;
    #pragma unroll
    for (int rt = 0; rt < 4; ++rt) {
        float own[4], oth[4], tij[8];
        #pragma unroll
        for (int j = 0; j < 4; ++j) own[j] = acc[rt][j];
        #pragma unroll
        for (int j = 0; j < 4; ++j) oth[j] = __shfl_xor(own[j], 16);
        if ((quad & 1) == 0) {
            #pragma unroll
            for (int j = 0; j < 4; ++j) { tij[j] = own[j]; tij[4 + j] = oth[j]; }
        } else {
            #pragma unroll
            for (int j = 0; j < 4; ++j) { tij[j] = oth[j]; tij[4 + j] = own[j]; }
        }
        #pragma unroll
        for (int oo = 0; oo < 4; ++oo) {
            float v = 0.f;
            #pragma unroll
            for (int j = 0; j < 8; ++j) v += w1_s[(oib + oo) * 8 + j] * tij[j];
            vs[(wave * 16 + p * 8 + oib + oo) * LSTR + rt * 16 + col] = f2bf(v);
        }
    }
    __syncthreads();   // vs complete -> va loads

    // ---- stage 3: out[32 x 512] = v[32 x 64] @ a^T, in 4 ok-groups of
    // 128. Swapped operands: C[ok][xrow]. C bounces through ct LDS tile,
    // then streams out as linear 2KB/instr full-line NT stores.
    s16x8 va[2][2];
    #pragma unroll
    for (int m = 0; m < 2; ++m) {
        const unsigned short* vp = &vs[(m * 16 + col) * LSTR + quad * 8];
        va[m][0] = *(const s16x8*)(vp);
        va[m][1] = *(const s16x8*)(vp + 32);
    }
    __syncthreads();   // va reads drained before ct overwrites vs (alias)

    const int srow = t >> 5;          // 0..3: store-row within 4-row band
    const int scol = (t & 31) * 4;    // 0..124: float col within 128-group

    for (int g = 0; g < 4; ++g) {
        // wave w covers local ok [w*64, w*64+64) of this group's 128.
        #pragma unroll
        for (int j = 0; j < 4; ++j) {
            const int okl = wave * 64 + j * 16;   // local ok base
            const unsigned short* ag = a_bf + (g * 128 + okl + col) * 64 + quad * 8;
            s16x8 af0 = *(const s16x8*)(ag);
            s16x8 af1 = *(const s16x8*)(ag + 32);
            #pragma unroll
            for (int m = 0; m < 2; ++m) {
                f32x4 c = {0.f, 0.f, 0.f, 0.f};
                c = __builtin_amdgcn_mfma_f32_16x16x32_bf16(af0, va[m][0], c, 0, 0, 0);
                c = __builtin_amdgcn_mfma_f32_16x16x32_bf16(af1, va[m][1], c, 0, 0, 0);
                // C row = okl + quad*4 + reg (local ok), C col = m*16+col (xrow)
                *(f32x4*)&ct[(m * 16 + col) * CSTR + okl + quad * 4] = c;
            }
        }
        __syncthreads();   // ct complete
        // stream 16KB: 8 instrs x 128 thr x 16B; each instr = 4 rows x
        // 512B aligned contiguous chunks -> full-line NT write-combining.
        float* og = out + (rowbase + srow) * 512 + g * 128 + scol;
        #pragma unroll
        for (int i = 0; i < 8; ++i) {
            f32x4 cv = *(const f32x4*)&ct[(i * 4 + srow) * CSTR + scol];
            __builtin_nontemporal_store(cv, (f32x4*)(og + (long)i * 4 * 512));
        }
        if (g < 3) __syncthreads();   // before next group's ct overwrite
    }
}

extern "C" void kernel_launch(void* const* d_in, const int* in_sizes, int n_in,
                              void* d_out, int out_size, void* d_ws, size_t ws_size,
                              hipStream_t stream) {
    const float* x  = (const float*)d_in[0];  // [4,2048,4096]
    const float* w1 = (const float*)d_in[1];  // [8,8]
    const float* a  = (const float*)d_in[2];  // [512,64]
    const float* b  = (const float*)d_in[3];  // [64,512]

    unsigned short* b_bf = (unsigned short*)d_ws;          // 64 KB
    unsigned short* a_bf = b_bf + 32768;                   // 64 KB
    float*          w1s  = (float*)(a_bf + 32768);         // 256 B

    lokr_pre<<<128, 256, 0, stream>>>(w1, a, b, b_bf, a_bf, w1s);
    lokr_main<<<2048, 128, 0, stream>>>(x, b_bf, a_bf, w1s, (float*)d_out);
}